// Round 1
// 694.373 us; speedup vs baseline: 1.0984x; 1.0984x over previous
//
#include <hip/hip_runtime.h>
#include <stdint.h>
#include <math.h>

// Problem constants (B=2,S=2048,H=1024,E=8,K=2,F=4096)
#define T_TOK 4096
#define H_DIM 1024
#define E_EXP 8
#define F_DIM 4096
#define NASSIGN (T_TOK * 2)
#define OUT_ELEMS ((size_t)T_TOK * H_DIM)

typedef unsigned short u16;
typedef __attribute__((ext_vector_type(8))) short short8;   // 8 bf16 = 4 VGPRs
typedef __attribute__((ext_vector_type(4))) float f32x4;

__device__ __forceinline__ u16 f2bf(float f) {
  union { float f; uint32_t u; } c; c.f = f;
  uint32_t u = c.u;
  return (u16)((u + 0x7FFFu + ((u >> 16) & 1u)) >> 16);  // RNE
}

// async global->LDS, 16B per lane. LDS dest is wave-uniform base + lane*16.
__device__ __forceinline__ void gl_lds16(const void* g, void* l) {
  __builtin_amdgcn_global_load_lds(
      (const __attribute__((address_space(1))) uint32_t*)g,
      (__attribute__((address_space(3))) uint32_t*)(uintptr_t)l, 16, 0, 0);
}

// ---------------- weight convert+transpose to tiled layout ----------------
// in: [E][R][C] fp32 (R = K-dim, C = N-dim)
// out: [E][C/64][R/64][64][64] bf16, inner tile [c-local][r-local], r contiguous.
__global__ __launch_bounds__(256) void transpose_cvt_tiled(
    const float* __restrict__ in, u16* __restrict__ out, int R, int C) {
  __shared__ u16 tile[64][72];
  const size_t eoff = (size_t)blockIdx.z * R * C;
  {
    const int c4 = (threadIdx.x & 15) * 4;
    const int rr = threadIdx.x >> 4;
    const float* inp = in + eoff + ((size_t)blockIdx.y * 64) * C + blockIdx.x * 64;
#pragma unroll
    for (int p = 0; p < 4; ++p) {
      const int r = rr + p * 16;
      const float4 v = *(const float4*)(inp + (size_t)r * C + c4);
      tile[r][c4 + 0] = f2bf(v.x); tile[r][c4 + 1] = f2bf(v.y);
      tile[r][c4 + 2] = f2bf(v.z); tile[r][c4 + 3] = f2bf(v.w);
    }
  }
  __syncthreads();
  {
    u16* op = out + (((size_t)blockIdx.z * (C >> 6) + blockIdx.x) * (R >> 6)
                     + blockIdx.y) * 4096;
#pragma unroll
    for (int p = 0; p < 2; ++p) {
      const int c = (threadIdx.x >> 3) + p * 32;
      const int rg = (threadIdx.x & 7) * 8;
      short8 o;
#pragma unroll
      for (int j = 0; j < 8; ++j) o[j] = (short)tile[rg + j][c];
      *(short8*)(op + c * 64 + rg) = o;
    }
  }
}

// ---------------- router (fused x fp32->bf16 conversion) ----------------
__global__ void router_kernel(const float* __restrict__ x, const float* __restrict__ Wr,
                              const float* __restrict__ br, u16* __restrict__ xb,
                              int* __restrict__ tki, float* __restrict__ tkw,
                              int* __restrict__ counts, float* __restrict__ zsum) {
  const int wave = threadIdx.x >> 6;
  const int lane = threadIdx.x & 63;
  const int t = blockIdx.x * 4 + wave;
  const float* xr = x + (size_t)t * H_DIM;
  u16* xbr = xb + (size_t)t * H_DIM;
  float acc[8];
#pragma unroll
  for (int e = 0; e < 8; ++e) acc[e] = 0.0f;
#pragma unroll
  for (int j = 0; j < 16; ++j) {
    const int hh = j * 64 + lane;
    const float xv = xr[hh];
    xbr[hh] = f2bf(xv);
    const float4 w0 = *(const float4*)(Wr + (size_t)hh * 8);
    const float4 w1 = *(const float4*)(Wr + (size_t)hh * 8 + 4);
    acc[0] += xv * w0.x; acc[1] += xv * w0.y; acc[2] += xv * w0.z; acc[3] += xv * w0.w;
    acc[4] += xv * w1.x; acc[5] += xv * w1.y; acc[6] += xv * w1.z; acc[7] += xv * w1.w;
  }
#pragma unroll
  for (int e = 0; e < 8; ++e) {
    float v = acc[e];
#pragma unroll
    for (int s = 32; s > 0; s >>= 1) v += __shfl_xor(v, s);
    acc[e] = v;
  }
  if (lane == 0) {
    float l[8];
#pragma unroll
    for (int e = 0; e < 8; ++e) l[e] = acc[e] + br[e];
    float mx = l[0];
#pragma unroll
    for (int e = 1; e < 8; ++e) mx = fmaxf(mx, l[e]);
    float p[8], s = 0.0f;
#pragma unroll
    for (int e = 0; e < 8; ++e) { p[e] = __expf(l[e] - mx); s += p[e]; }
    int i0 = 0;
#pragma unroll
    for (int e = 1; e < 8; ++e) if (p[e] > p[i0]) i0 = e;
    int i1 = (i0 == 0) ? 1 : 0;
#pragma unroll
    for (int e = 0; e < 8; ++e) if (e != i1 && e != i0 && p[e] > p[i1]) i1 = e;
    const float ws = p[i0] + p[i1];
    tki[2 * t] = i0; tki[2 * t + 1] = i1;
    tkw[2 * t] = p[i0] / ws; tkw[2 * t + 1] = p[i1] / ws;
    atomicAdd(&counts[i0], 1);
    atomicAdd(&counts[i1], 1);
    atomicAdd(zsum, mx + logf(s));
  }
}

// scatter + (block 0) loss. Each block computes the 8-wide prefix locally.
// Also records the token->slot map (islot) for the final combine.
__global__ void scatter_kernel(const int* __restrict__ tki, const float* __restrict__ tkw,
                               const int* __restrict__ counts, int* __restrict__ cursor,
                               int* __restrict__ perm, float* __restrict__ pw,
                               int* __restrict__ islot,
                               const float* __restrict__ zsum, float* __restrict__ out_loss) {
  int offs[8];
  {
    int a = 0;
#pragma unroll
    for (int e = 0; e < 8; ++e) { offs[e] = a; a += counts[e]; }
  }
  const int t = blockIdx.x * 256 + threadIdx.x;
#pragma unroll
  for (int k = 0; k < 2; ++k) {
    const int e = tki[2 * t + k];
    const int p = atomicAdd(&cursor[e], 1);
    const int slot = offs[e] + p;
    perm[slot] = t;
    pw[slot] = tkw[2 * t + k];
    islot[2 * t + k] = slot;
  }
  if (blockIdx.x == 0 && threadIdx.x == 0) {
    float aux = 0.0f;
#pragma unroll
    for (int e = 0; e < 8; ++e) {
      const float d = (float)counts[e] / (float)NASSIGN - 0.125f;
      aux += d * d;
    }
    aux *= (1.0f / 8.0f);
    out_loss[0] = 0.01f * aux + 0.001f * (zsum[0] / (float)T_TOK);
  }
}

// ---------------- grouped GEMMs: 128x128 tile, BK=64, XOR-swizzled staging ----------------
// Grid is 1D; id&7 = expert -> XCD (round-robin heuristic) so each expert's
// working set (A-stripe + B k-chunk, ~4MB) stays in one XCD's L2.

// h[slot][F] = gelu( xb[perm[slot]] @ W1t[e]^T + b1[e] )  (bf16 out)
__global__ __launch_bounds__(256, 4) void gemm1_kernel(
    const u16* __restrict__ xb, const u16* __restrict__ w1t,
    const float* __restrict__ b1, const int* __restrict__ perm,
    const int* __restrict__ cnts, u16* __restrict__ hbuf) {
  const int id = blockIdx.x;
  const int e = id & 7;               // XCD group
  const int wq = id >> 3;
  const int n0 = (wq & 31) << 7;      // 32 n-blocks
  const int m0 = (wq >> 5) << 7;      // m outer: live blocks dispatch first
  int cnt, off;
  {
    int a = 0, c = 0;
#pragma unroll
    for (int i = 0; i < 8; ++i) { const int ci = cnts[i]; if (i < e) a += ci; if (i == e) c = ci; }
    cnt = c; off = a;
  }
  if (m0 >= cnt) return;

  __shared__ __align__(16) u16 smem[16384];   // As 8192 + Bs 8192; epilogue reuses all 32KB
  u16* As = smem;
  u16* Bs = smem + 8192;

  const int tid = threadIdx.x;
  const int rbase = tid >> 3;
  const int kc = ((tid & 7) ^ (rbase & 7)) * 8;

  const u16* ap[4];
#pragma unroll
  for (int l = 0; l < 4; ++l) {
    int ra = m0 + rbase + l * 32; if (ra > cnt - 1) ra = cnt - 1;
    ap[l] = xb + (size_t)perm[off + ra] * H_DIM + kc;
  }
  const u16* bp0 = w1t + ((((size_t)e * (F_DIM >> 6) + (n0 >> 6)) * (H_DIM >> 6)) << 12)
                 + rbase * 64 + kc;
  const size_t bnt = (size_t)(H_DIM >> 6) << 12;

  const int wave = tid >> 6, lane = tid & 63;
  const int wm = (wave >> 1) * 64, wn = (wave & 1) * 64;
  const int lr = lane & 15, q = lane >> 4;
  const int qs0 = q ^ (lr & 7), qs1 = (4 + q) ^ (lr & 7);

  f32x4 acc[4][4];
#pragma unroll
  for (int i = 0; i < 4; ++i)
#pragma unroll
    for (int j = 0; j < 4; ++j) acc[i][j] = (f32x4)0.0f;

  const short8* Afr = (const short8*)As;
  const short8* Bfr = (const short8*)Bs;

  for (int k0 = 0; k0 < (H_DIM >> 6); ++k0) {
    gl_lds16(ap[0], &As[(size_t)tid * 8]);
    gl_lds16(ap[1], &As[(size_t)(tid + 256) * 8]);
    gl_lds16(ap[2], &As[(size_t)(tid + 512) * 8]);
    gl_lds16(ap[3], &As[(size_t)(tid + 768) * 8]);
    gl_lds16(bp0,              &Bs[(size_t)tid * 8]);
    gl_lds16(bp0 + 2048,       &Bs[(size_t)(tid + 256) * 8]);
    gl_lds16(bp0 + bnt,        &Bs[(size_t)(tid + 512) * 8]);
    gl_lds16(bp0 + bnt + 2048, &Bs[(size_t)(tid + 768) * 8]);
#pragma unroll
    for (int l = 0; l < 4; ++l) ap[l] += 64;
    bp0 += 4096;
    __syncthreads();
#pragma unroll
    for (int s = 0; s < 2; ++s) {
      const int qs = s ? qs1 : qs0;
      short8 a[4], b[4];
#pragma unroll
      for (int i = 0; i < 4; ++i) a[i] = Afr[(wm + i * 16 + lr) * 8 + qs];
#pragma unroll
      for (int j = 0; j < 4; ++j) b[j] = Bfr[(wn + j * 16 + lr) * 8 + qs];
#pragma unroll
      for (int i = 0; i < 4; ++i)
#pragma unroll
        for (int j = 0; j < 4; ++j)
          acc[i][j] = __builtin_amdgcn_mfma_f32_16x16x32_bf16(a[i], b[j], acc[i][j], 0, 0, 0);
    }
    __syncthreads();
  }

  // Epilogue: bias+gelu -> bf16 -> LDS (XOR col swizzle by row-quad) -> 16B stores.
#pragma unroll
  for (int i = 0; i < 4; ++i) {
#pragma unroll
    for (int rr = 0; rr < 4; ++rr) {
      const int row = wm + i * 16 + q * 4 + rr;
#pragma unroll
      for (int j = 0; j < 4; ++j) {
        const int col = wn + j * 16 + lr;
        const float v = acc[i][j][rr] + b1[e * F_DIM + n0 + col];
        const float g = 0.5f * v * (1.0f + erff(v * 0.70710678118654752f));
        smem[(row << 7) + (col ^ (q << 4))] = f2bf(g);
      }
    }
  }
  __syncthreads();
#pragma unroll
  for (int p = 0; p < 8; ++p) {
    const int ml = p * 16 + (tid >> 4);
    const int nl = (tid & 15) * 8;
    const int m = m0 + ml;
    if (m < cnt) {
      const int qq = (ml >> 2) & 3;
      *(short8*)(hbuf + (size_t)(off + m) * F_DIM + n0 + nl) =
          *(const short8*)(smem + (ml << 7) + (nl ^ (qq << 4)));
    }
  }
}

// ybuf[slot] = w_slot * (h[slot] @ W2t[e]^T + b2[e])   -- full K, no atomics
__global__ __launch_bounds__(256, 4) void gemm2_kernel(
    const u16* __restrict__ hbuf, const u16* __restrict__ w2t,
    const float* __restrict__ b2, const float* __restrict__ pw,
    const int* __restrict__ cnts, float* __restrict__ ybuf) {
  const int id = blockIdx.x;
  const int e = id & 7;               // XCD group
  const int wq = id >> 3;
  const int n0 = (wq & 7) << 7;       // 8 n-blocks
  const int m0 = (wq >> 3) << 7;      // m outer
  int cnt, off;
  {
    int a = 0, c = 0;
#pragma unroll
    for (int i = 0; i < 8; ++i) { const int ci = cnts[i]; if (i < e) a += ci; if (i == e) c = ci; }
    cnt = c; off = a;
  }
  if (m0 >= cnt) return;

  __shared__ __align__(16) u16 As[128 * 64];
  __shared__ __align__(16) u16 Bs[128 * 64];

  const int tid = threadIdx.x;
  const int rbase = tid >> 3;
  const int kc = ((tid & 7) ^ (rbase & 7)) * 8;

  const u16* ap[4];
#pragma unroll
  for (int l = 0; l < 4; ++l) {
    int ra = m0 + rbase + l * 32; if (ra > cnt - 1) ra = cnt - 1;
    ap[l] = hbuf + (size_t)(off + ra) * F_DIM + kc;
  }
  const u16* bp0 = w2t + ((((size_t)e * (H_DIM >> 6) + (n0 >> 6)) * (F_DIM >> 6)) << 12)
                 + rbase * 64 + kc;
  const size_t bnt = (size_t)(F_DIM >> 6) << 12;

  const int wave = tid >> 6, lane = tid & 63;
  const int wm = (wave >> 1) * 64, wn = (wave & 1) * 64;
  const int lr = lane & 15, q = lane >> 4;
  const int qs0 = q ^ (lr & 7), qs1 = (4 + q) ^ (lr & 7);

  f32x4 acc[4][4];
#pragma unroll
  for (int i = 0; i < 4; ++i)
#pragma unroll
    for (int j = 0; j < 4; ++j) acc[i][j] = (f32x4)0.0f;

  const short8* Afr = (const short8*)As;
  const short8* Bfr = (const short8*)Bs;

  for (int k0 = 0; k0 < (F_DIM >> 6); ++k0) {   // 4096 / 64 = 64 iters, full K
    gl_lds16(ap[0], &As[(size_t)tid * 8]);
    gl_lds16(ap[1], &As[(size_t)(tid + 256) * 8]);
    gl_lds16(ap[2], &As[(size_t)(tid + 512) * 8]);
    gl_lds16(ap[3], &As[(size_t)(tid + 768) * 8]);
    gl_lds16(bp0,              &Bs[(size_t)tid * 8]);
    gl_lds16(bp0 + 2048,       &Bs[(size_t)(tid + 256) * 8]);
    gl_lds16(bp0 + bnt,        &Bs[(size_t)(tid + 512) * 8]);
    gl_lds16(bp0 + bnt + 2048, &Bs[(size_t)(tid + 768) * 8]);
#pragma unroll
    for (int l = 0; l < 4; ++l) ap[l] += 64;
    bp0 += 4096;
    __syncthreads();
#pragma unroll
    for (int s = 0; s < 2; ++s) {
      const int qs = s ? qs1 : qs0;
      short8 a[4], b[4];
#pragma unroll
      for (int i = 0; i < 4; ++i) a[i] = Afr[(wm + i * 16 + lr) * 8 + qs];
#pragma unroll
      for (int j = 0; j < 4; ++j) b[j] = Bfr[(wn + j * 16 + lr) * 8 + qs];
#pragma unroll
      for (int i = 0; i < 4; ++i)
#pragma unroll
        for (int j = 0; j < 4; ++j)
          acc[i][j] = __builtin_amdgcn_mfma_f32_16x16x32_bf16(a[i], b[j], acc[i][j], 0, 0, 0);
    }
    __syncthreads();
  }

  // Epilogue: per-slot weighted output, plain f32 stores (no atomics).
#pragma unroll
  for (int i = 0; i < 4; ++i) {
#pragma unroll
    for (int rr = 0; rr < 4; ++rr) {
      const int m = m0 + wm + i * 16 + q * 4 + rr;
      if (m < cnt) {
        const int slot = off + m;
        const float w = pw[slot];
        float* orow = ybuf + (size_t)slot * H_DIM;
#pragma unroll
        for (int j = 0; j < 4; ++j) {
          const int col = n0 + wn + j * 16 + lr;
          orow[col] = w * (acc[i][j][rr] + b2[e * H_DIM + col]);
        }
      }
    }
  }
}

// out[t] = ybuf[slot0(t)] + ybuf[slot1(t)]
__global__ __launch_bounds__(256) void combine_kernel(
    const float* __restrict__ ybuf, const int* __restrict__ islot,
    float* __restrict__ out) {
  const int t = blockIdx.x;
  const int s0 = islot[2 * t];
  const int s1 = islot[2 * t + 1];
  const int c = threadIdx.x * 4;
  const float4 a = *(const float4*)(ybuf + (size_t)s0 * H_DIM + c);
  const float4 b = *(const float4*)(ybuf + (size_t)s1 * H_DIM + c);
  float4 r;
  r.x = a.x + b.x; r.y = a.y + b.y; r.z = a.z + b.z; r.w = a.w + b.w;
  *(float4*)(out + (size_t)t * H_DIM + c) = r;
}

// ---------------- launch ----------------

extern "C" void kernel_launch(void* const* d_in, const int* in_sizes, int n_in,
                              void* d_out, int out_size, void* d_ws, size_t ws_size,
                              hipStream_t stream) {
  const float* x  = (const float*)d_in[0];
  const float* Wr = (const float*)d_in[1];
  const float* br = (const float*)d_in[2];
  const float* W1 = (const float*)d_in[3];
  const float* b1 = (const float*)d_in[4];
  const float* W2 = (const float*)d_in[5];
  const float* b2 = (const float*)d_in[6];
  float* out = (float*)d_out;

  // workspace layout (~210 MB)
  char* ws = (char*)d_ws;
  u16* xb    = (u16*)(ws);                          // 8 MB
  u16* w1t   = (u16*)(ws + 8388608ull);             // 64 MB  tiled [E][F/64][H/64][64][64]
  u16* w2t   = (u16*)(ws + 75497472ull);            // 64 MB  tiled [E][H/64][F/64][64][64]
  u16* hbuf  = (u16*)(ws + 142606336ull);           // 64 MB  [8192][F] bf16
  // ybuf reuses w1t's 64MB region: w1t is dead after gemm1, ybuf written by gemm2.
  float* ybuf = (float*)(ws + 8388608ull);          // 32 MB  [8192][H] f32
  int*   tki    = (int*)(ws + 209715200ull);
  float* tkw    = (float*)(ws + 209747968ull);
  int*   perm   = (int*)(ws + 209780736ull);
  float* pw     = (float*)(ws + 209813504ull);
  int*   counts = (int*)(ws + 209846272ull);        // counts[8], cursor[8], zsum
  int*   cursor = counts + 8;
  float* zsum   = (float*)(counts + 16);
  int*   islot  = (int*)(ws + 209846400ull);        // 32 KB  [T][2] slot map

  hipMemsetAsync(counts, 0, 128, stream);

  // W1 [E][H][F]: R=H(K), C=F(N) -> tiles [E][F/64][H/64]
  transpose_cvt_tiled<<<dim3(F_DIM / 64, H_DIM / 64, E_EXP), 256, 0, stream>>>(W1, w1t, H_DIM, F_DIM);
  // W2 [E][F][H]: R=F(K), C=H(N) -> tiles [E][H/64][F/64]
  transpose_cvt_tiled<<<dim3(H_DIM / 64, F_DIM / 64, E_EXP), 256, 0, stream>>>(W2, w2t, F_DIM, H_DIM);
  router_kernel<<<T_TOK / 4, 256, 0, stream>>>(x, Wr, br, xb, tki, tkw, counts, zsum);
  scatter_kernel<<<T_TOK / 256, 256, 0, stream>>>(tki, tkw, counts, cursor, perm, pw,
                                                  islot, zsum, out + OUT_ELEMS);
  gemm1_kernel<<<8192, 256, 0, stream>>>(xb, w1t, b1, perm, counts, hbuf);
  // 8 experts x 8 n-blocks x up to 32 m-blocks
  gemm2_kernel<<<2048, 256, 0, stream>>>(hbuf, w2t, b2, pw, counts, ybuf);
  combine_kernel<<<T_TOK, 256, 0, stream>>>(ybuf, islot, out);
}

// Round 2
// 608.072 us; speedup vs baseline: 1.2543x; 1.1419x over previous
//
#include <hip/hip_runtime.h>
#include <stdint.h>
#include <math.h>

// Problem constants (B=2,S=2048,H=1024,E=8,K=2,F=4096)
#define T_TOK 4096
#define H_DIM 1024
#define E_EXP 8
#define F_DIM 4096
#define NASSIGN (T_TOK * 2)
#define OUT_ELEMS ((size_t)T_TOK * H_DIM)
#define YB_ELEMS ((size_t)8192 * H_DIM)   // one split-K slab: [8192][H] f32

typedef unsigned short u16;
typedef __attribute__((ext_vector_type(8))) short short8;   // 8 bf16 = 4 VGPRs
typedef __attribute__((ext_vector_type(4))) float f32x4;

__device__ __forceinline__ u16 f2bf(float f) {
  union { float f; uint32_t u; } c; c.f = f;
  uint32_t u = c.u;
  return (u16)((u + 0x7FFFu + ((u >> 16) & 1u)) >> 16);  // RNE
}

// async global->LDS, 16B per lane. LDS dest is wave-uniform base + lane*16.
__device__ __forceinline__ void gl_lds16(const void* g, void* l) {
  __builtin_amdgcn_global_load_lds(
      (const __attribute__((address_space(1))) uint32_t*)g,
      (__attribute__((address_space(3))) uint32_t*)(uintptr_t)l, 16, 0, 0);
}

// ---------------- weight convert+transpose to tiled layout ----------------
// in: [E][R][C] fp32 (R = K-dim, C = N-dim)
// out: [E][C/64][R/64][64][64] bf16, inner tile [c-local][r-local], r contiguous.
__global__ __launch_bounds__(256) void transpose_cvt_tiled(
    const float* __restrict__ in, u16* __restrict__ out, int R, int C) {
  __shared__ u16 tile[64][72];
  const size_t eoff = (size_t)blockIdx.z * R * C;
  {
    const int c4 = (threadIdx.x & 15) * 4;
    const int rr = threadIdx.x >> 4;
    const float* inp = in + eoff + ((size_t)blockIdx.y * 64) * C + blockIdx.x * 64;
#pragma unroll
    for (int p = 0; p < 4; ++p) {
      const int r = rr + p * 16;
      const float4 v = *(const float4*)(inp + (size_t)r * C + c4);
      tile[r][c4 + 0] = f2bf(v.x); tile[r][c4 + 1] = f2bf(v.y);
      tile[r][c4 + 2] = f2bf(v.z); tile[r][c4 + 3] = f2bf(v.w);
    }
  }
  __syncthreads();
  {
    u16* op = out + (((size_t)blockIdx.z * (C >> 6) + blockIdx.x) * (R >> 6)
                     + blockIdx.y) * 4096;
#pragma unroll
    for (int p = 0; p < 2; ++p) {
      const int c = (threadIdx.x >> 3) + p * 32;
      const int rg = (threadIdx.x & 7) * 8;
      short8 o;
#pragma unroll
      for (int j = 0; j < 8; ++j) o[j] = (short)tile[rg + j][c];
      *(short8*)(op + c * 64 + rg) = o;
    }
  }
}

// ---------------- router (fused x fp32->bf16 conversion) ----------------
// 16 tokens per block (4 waves x 4 tokens). Counts/z aggregated in LDS;
// global atomics reduced from 12288 to 256 blocks x <=9.
__global__ void router_kernel(const float* __restrict__ x, const float* __restrict__ Wr,
                              const float* __restrict__ br, u16* __restrict__ xb,
                              int* __restrict__ tki, float* __restrict__ tkw,
                              int* __restrict__ counts, float* __restrict__ zsum) {
  const int wave = threadIdx.x >> 6;
  const int lane = threadIdx.x & 63;
  __shared__ int lcnt[8];
  __shared__ float lzv[16];
  if (threadIdx.x < 8) lcnt[threadIdx.x] = 0;
  __syncthreads();
#pragma unroll
  for (int it = 0; it < 4; ++it) {
    const int t = blockIdx.x * 16 + wave * 4 + it;
    const float* xr = x + (size_t)t * H_DIM;
    u16* xbr = xb + (size_t)t * H_DIM;
    float acc[8];
#pragma unroll
    for (int e = 0; e < 8; ++e) acc[e] = 0.0f;
#pragma unroll
    for (int j = 0; j < 16; ++j) {
      const int hh = j * 64 + lane;
      const float xv = xr[hh];
      xbr[hh] = f2bf(xv);
      const float4 w0 = *(const float4*)(Wr + (size_t)hh * 8);
      const float4 w1 = *(const float4*)(Wr + (size_t)hh * 8 + 4);
      acc[0] += xv * w0.x; acc[1] += xv * w0.y; acc[2] += xv * w0.z; acc[3] += xv * w0.w;
      acc[4] += xv * w1.x; acc[5] += xv * w1.y; acc[6] += xv * w1.z; acc[7] += xv * w1.w;
    }
#pragma unroll
    for (int e = 0; e < 8; ++e) {
      float v = acc[e];
#pragma unroll
      for (int s = 32; s > 0; s >>= 1) v += __shfl_xor(v, s);
      acc[e] = v;
    }
    if (lane == 0) {
      float l[8];
#pragma unroll
      for (int e = 0; e < 8; ++e) l[e] = acc[e] + br[e];
      float mx = l[0];
#pragma unroll
      for (int e = 1; e < 8; ++e) mx = fmaxf(mx, l[e]);
      float p[8], s = 0.0f;
#pragma unroll
      for (int e = 0; e < 8; ++e) { p[e] = __expf(l[e] - mx); s += p[e]; }
      int i0 = 0;
#pragma unroll
      for (int e = 1; e < 8; ++e) if (p[e] > p[i0]) i0 = e;
      int i1 = (i0 == 0) ? 1 : 0;
#pragma unroll
      for (int e = 0; e < 8; ++e) if (e != i1 && e != i0 && p[e] > p[i1]) i1 = e;
      const float ws = p[i0] + p[i1];
      tki[2 * t] = i0; tki[2 * t + 1] = i1;
      tkw[2 * t] = p[i0] / ws; tkw[2 * t + 1] = p[i1] / ws;
      atomicAdd(&lcnt[i0], 1);
      atomicAdd(&lcnt[i1], 1);
      lzv[wave * 4 + it] = mx + logf(s);
    }
  }
  __syncthreads();
  if (threadIdx.x < 8) {
    const int c = lcnt[threadIdx.x];
    if (c) atomicAdd(&counts[threadIdx.x], c);
  }
  if (threadIdx.x == 64) {
    float zs = 0.0f;
#pragma unroll
    for (int i = 0; i < 16; ++i) zs += lzv[i];
    atomicAdd(zsum, zs);
  }
}

// scatter + (block 0) loss. Per-wave ballot aggregation: one cursor atomic
// per (wave, expert, k) instead of per assignment (8192 -> ~1024 atomics).
__global__ void scatter_kernel(const int* __restrict__ tki, const float* __restrict__ tkw,
                               const int* __restrict__ counts, int* __restrict__ cursor,
                               int* __restrict__ perm, float* __restrict__ pw,
                               int* __restrict__ islot,
                               const float* __restrict__ zsum, float* __restrict__ out_loss) {
  int offs[8];
  {
    int a = 0;
#pragma unroll
    for (int e = 0; e < 8; ++e) { offs[e] = a; a += counts[e]; }
  }
  const int lane = threadIdx.x & 63;
  const int t = blockIdx.x * 256 + threadIdx.x;
#pragma unroll
  for (int k = 0; k < 2; ++k) {
    const int e = tki[2 * t + k];
    int slot = 0;
#pragma unroll
    for (int ee = 0; ee < 8; ++ee) {
      const unsigned long long mask = __ballot(e == ee);
      if (mask) {
        const int leader = __ffsll(mask) - 1;
        int b = 0;
        if (lane == leader) b = atomicAdd(&cursor[ee], (int)__popcll(mask));
        b = __shfl(b, leader);
        if (e == ee) {
          const int r = (int)__popcll(mask & ((1ull << lane) - 1ull));
          slot = offs[ee] + b + r;
        }
      }
    }
    perm[slot] = t;
    pw[slot] = tkw[2 * t + k];
    islot[2 * t + k] = slot;
  }
  if (blockIdx.x == 0 && threadIdx.x == 0) {
    float aux = 0.0f;
#pragma unroll
    for (int e = 0; e < 8; ++e) {
      const float d = (float)counts[e] / (float)NASSIGN - 0.125f;
      aux += d * d;
    }
    aux *= (1.0f / 8.0f);
    out_loss[0] = 0.01f * aux + 0.001f * (zsum[0] / (float)T_TOK);
  }
}

// ---------------- grouped GEMMs: 128x128 tile, BK=64, XOR-swizzled staging ----------------
// Grid is 1D; id&7 = expert -> XCD (round-robin heuristic).

// h[slot][F] = gelu( xb[perm[slot]] @ W1t[e]^T + b1[e] )  (bf16 out)
__global__ __launch_bounds__(256, 4) void gemm1_kernel(
    const u16* __restrict__ xb, const u16* __restrict__ w1t,
    const float* __restrict__ b1, const int* __restrict__ perm,
    const int* __restrict__ cnts, u16* __restrict__ hbuf) {
  const int id = blockIdx.x;
  const int e = id & 7;               // XCD group
  const int wq = id >> 3;
  const int n0 = (wq & 31) << 7;      // 32 n-blocks
  const int m0 = (wq >> 5) << 7;      // m outer: live blocks dispatch first
  int cnt, off;
  {
    int a = 0, c = 0;
#pragma unroll
    for (int i = 0; i < 8; ++i) { const int ci = cnts[i]; if (i < e) a += ci; if (i == e) c = ci; }
    cnt = c; off = a;
  }
  if (m0 >= cnt) return;

  __shared__ __align__(16) u16 smem[16384];   // As 8192 + Bs 8192; epilogue reuses all 32KB
  u16* As = smem;
  u16* Bs = smem + 8192;

  const int tid = threadIdx.x;
  const int rbase = tid >> 3;
  const int kc = ((tid & 7) ^ (rbase & 7)) * 8;

  const u16* ap[4];
#pragma unroll
  for (int l = 0; l < 4; ++l) {
    int ra = m0 + rbase + l * 32; if (ra > cnt - 1) ra = cnt - 1;
    ap[l] = xb + (size_t)perm[off + ra] * H_DIM + kc;
  }
  const u16* bp0 = w1t + ((((size_t)e * (F_DIM >> 6) + (n0 >> 6)) * (H_DIM >> 6)) << 12)
                 + rbase * 64 + kc;
  const size_t bnt = (size_t)(H_DIM >> 6) << 12;

  const int wave = tid >> 6, lane = tid & 63;
  const int wm = (wave >> 1) * 64, wn = (wave & 1) * 64;
  const int lr = lane & 15, q = lane >> 4;
  const int qs0 = q ^ (lr & 7), qs1 = (4 + q) ^ (lr & 7);

  f32x4 acc[4][4];
#pragma unroll
  for (int i = 0; i < 4; ++i)
#pragma unroll
    for (int j = 0; j < 4; ++j) acc[i][j] = (f32x4)0.0f;

  const short8* Afr = (const short8*)As;
  const short8* Bfr = (const short8*)Bs;

  for (int k0 = 0; k0 < (H_DIM >> 6); ++k0) {
    gl_lds16(ap[0], &As[(size_t)tid * 8]);
    gl_lds16(ap[1], &As[(size_t)(tid + 256) * 8]);
    gl_lds16(ap[2], &As[(size_t)(tid + 512) * 8]);
    gl_lds16(ap[3], &As[(size_t)(tid + 768) * 8]);
    gl_lds16(bp0,              &Bs[(size_t)tid * 8]);
    gl_lds16(bp0 + 2048,       &Bs[(size_t)(tid + 256) * 8]);
    gl_lds16(bp0 + bnt,        &Bs[(size_t)(tid + 512) * 8]);
    gl_lds16(bp0 + bnt + 2048, &Bs[(size_t)(tid + 768) * 8]);
#pragma unroll
    for (int l = 0; l < 4; ++l) ap[l] += 64;
    bp0 += 4096;
    __syncthreads();
#pragma unroll
    for (int s = 0; s < 2; ++s) {
      const int qs = s ? qs1 : qs0;
      short8 a[4], b[4];
#pragma unroll
      for (int i = 0; i < 4; ++i) a[i] = Afr[(wm + i * 16 + lr) * 8 + qs];
#pragma unroll
      for (int j = 0; j < 4; ++j) b[j] = Bfr[(wn + j * 16 + lr) * 8 + qs];
#pragma unroll
      for (int i = 0; i < 4; ++i)
#pragma unroll
        for (int j = 0; j < 4; ++j)
          acc[i][j] = __builtin_amdgcn_mfma_f32_16x16x32_bf16(a[i], b[j], acc[i][j], 0, 0, 0);
    }
    __syncthreads();
  }

  // Epilogue: bias+gelu -> bf16 -> LDS (XOR col swizzle by row-quad) -> 16B stores.
#pragma unroll
  for (int i = 0; i < 4; ++i) {
#pragma unroll
    for (int rr = 0; rr < 4; ++rr) {
      const int row = wm + i * 16 + q * 4 + rr;
#pragma unroll
      for (int j = 0; j < 4; ++j) {
        const int col = wn + j * 16 + lr;
        const float v = acc[i][j][rr] + b1[e * F_DIM + n0 + col];
        const float g = 0.5f * v * (1.0f + erff(v * 0.70710678118654752f));
        smem[(row << 7) + (col ^ (q << 4))] = f2bf(g);
      }
    }
  }
  __syncthreads();
#pragma unroll
  for (int p = 0; p < 8; ++p) {
    const int ml = p * 16 + (tid >> 4);
    const int nl = (tid & 15) * 8;
    const int m = m0 + ml;
    if (m < cnt) {
      const int qq = (ml >> 2) & 3;
      *(short8*)(hbuf + (size_t)(off + m) * F_DIM + n0 + nl) =
          *(const short8*)(smem + (ml << 7) + (nl ^ (qq << 4)));
    }
  }
}

// ybuf[ks][slot] = w_slot * (h[slot] @ W2t[e]^T [k-half ks] + (ks==0)*b2[e])
// split-K=2 over separate slabs -> no atomics, 2x occupancy.
__global__ __launch_bounds__(256, 4) void gemm2_kernel(
    const u16* __restrict__ hbuf, const u16* __restrict__ w2t,
    const float* __restrict__ b2, const float* __restrict__ pw,
    const int* __restrict__ cnts, float* __restrict__ ybuf) {
  const int id = blockIdx.x;
  const int e = id & 7;               // XCD group
  const int wq = id >> 3;
  const int n0 = (wq & 7) << 7;       // 8 n-blocks
  const int ks = (wq >> 3) & 1;       // 2 K-splits (2048 each)
  const int m0 = (wq >> 4) << 7;      // m outer
  int cnt, off;
  {
    int a = 0, c = 0;
#pragma unroll
    for (int i = 0; i < 8; ++i) { const int ci = cnts[i]; if (i < e) a += ci; if (i == e) c = ci; }
    cnt = c; off = a;
  }
  if (m0 >= cnt) return;

  __shared__ __align__(16) u16 As[128 * 64];
  __shared__ __align__(16) u16 Bs[128 * 64];

  const int tid = threadIdx.x;
  const int rbase = tid >> 3;
  const int kc = ((tid & 7) ^ (rbase & 7)) * 8;

  const u16* ap[4];
#pragma unroll
  for (int l = 0; l < 4; ++l) {
    int ra = m0 + rbase + l * 32; if (ra > cnt - 1) ra = cnt - 1;
    ap[l] = hbuf + (size_t)(off + ra) * F_DIM + (ks << 11) + kc;
  }
  const u16* bp0 = w2t + ((((size_t)e * (H_DIM >> 6) + (n0 >> 6)) * (F_DIM >> 6)) << 12)
                 + ((size_t)(ks << 5) << 12) + rbase * 64 + kc;
  const size_t bnt = (size_t)(F_DIM >> 6) << 12;

  const int wave = tid >> 6, lane = tid & 63;
  const int wm = (wave >> 1) * 64, wn = (wave & 1) * 64;
  const int lr = lane & 15, q = lane >> 4;
  const int qs0 = q ^ (lr & 7), qs1 = (4 + q) ^ (lr & 7);

  f32x4 acc[4][4];
#pragma unroll
  for (int i = 0; i < 4; ++i)
#pragma unroll
    for (int j = 0; j < 4; ++j) acc[i][j] = (f32x4)0.0f;

  const short8* Afr = (const short8*)As;
  const short8* Bfr = (const short8*)Bs;

  for (int k0 = 0; k0 < 32; ++k0) {   // 2048 / 64, half of K
    gl_lds16(ap[0], &As[(size_t)tid * 8]);
    gl_lds16(ap[1], &As[(size_t)(tid + 256) * 8]);
    gl_lds16(ap[2], &As[(size_t)(tid + 512) * 8]);
    gl_lds16(ap[3], &As[(size_t)(tid + 768) * 8]);
    gl_lds16(bp0,              &Bs[(size_t)tid * 8]);
    gl_lds16(bp0 + 2048,       &Bs[(size_t)(tid + 256) * 8]);
    gl_lds16(bp0 + bnt,        &Bs[(size_t)(tid + 512) * 8]);
    gl_lds16(bp0 + bnt + 2048, &Bs[(size_t)(tid + 768) * 8]);
#pragma unroll
    for (int l = 0; l < 4; ++l) ap[l] += 64;
    bp0 += 4096;
    __syncthreads();
#pragma unroll
    for (int s = 0; s < 2; ++s) {
      const int qs = s ? qs1 : qs0;
      short8 a[4], b[4];
#pragma unroll
      for (int i = 0; i < 4; ++i) a[i] = Afr[(wm + i * 16 + lr) * 8 + qs];
#pragma unroll
      for (int j = 0; j < 4; ++j) b[j] = Bfr[(wn + j * 16 + lr) * 8 + qs];
#pragma unroll
      for (int i = 0; i < 4; ++i)
#pragma unroll
        for (int j = 0; j < 4; ++j)
          acc[i][j] = __builtin_amdgcn_mfma_f32_16x16x32_bf16(a[i], b[j], acc[i][j], 0, 0, 0);
    }
    __syncthreads();
  }

  // Epilogue: per-slot weighted partial, plain f32 stores into slab ks.
  float* yb = ybuf + (size_t)ks * YB_ELEMS;
#pragma unroll
  for (int i = 0; i < 4; ++i) {
#pragma unroll
    for (int rr = 0; rr < 4; ++rr) {
      const int m = m0 + wm + i * 16 + q * 4 + rr;
      if (m < cnt) {
        const int slot = off + m;
        const float w = pw[slot];
        float* orow = yb + (size_t)slot * H_DIM;
#pragma unroll
        for (int j = 0; j < 4; ++j) {
          const int col = n0 + wn + j * 16 + lr;
          float y = acc[i][j][rr];
          if (ks == 0) y += b2[e * H_DIM + col];
          orow[col] = w * y;
        }
      }
    }
  }
}

// out[t] = sum over k of (ybuf0[slot_k] + ybuf1[slot_k])
__global__ __launch_bounds__(256) void combine_kernel(
    const float* __restrict__ ybuf, const int* __restrict__ islot,
    float* __restrict__ out) {
  const int t = blockIdx.x;
  const int s0 = islot[2 * t];
  const int s1 = islot[2 * t + 1];
  const int c = threadIdx.x * 4;
  const float4 a0 = *(const float4*)(ybuf + (size_t)s0 * H_DIM + c);
  const float4 a1 = *(const float4*)(ybuf + YB_ELEMS + (size_t)s0 * H_DIM + c);
  const float4 b0 = *(const float4*)(ybuf + (size_t)s1 * H_DIM + c);
  const float4 b1 = *(const float4*)(ybuf + YB_ELEMS + (size_t)s1 * H_DIM + c);
  float4 r;
  r.x = a0.x + a1.x + b0.x + b1.x;
  r.y = a0.y + a1.y + b0.y + b1.y;
  r.z = a0.z + a1.z + b0.z + b1.z;
  r.w = a0.w + a1.w + b0.w + b1.w;
  *(float4*)(out + (size_t)t * H_DIM + c) = r;
}

// ---------------- launch ----------------

extern "C" void kernel_launch(void* const* d_in, const int* in_sizes, int n_in,
                              void* d_out, int out_size, void* d_ws, size_t ws_size,
                              hipStream_t stream) {
  const float* x  = (const float*)d_in[0];
  const float* Wr = (const float*)d_in[1];
  const float* br = (const float*)d_in[2];
  const float* W1 = (const float*)d_in[3];
  const float* b1 = (const float*)d_in[4];
  const float* W2 = (const float*)d_in[5];
  const float* b2 = (const float*)d_in[6];
  float* out = (float*)d_out;

  // workspace layout (~210 MB)
  char* ws = (char*)d_ws;
  u16* xb    = (u16*)(ws);                          // 8 MB
  u16* w1t   = (u16*)(ws + 8388608ull);             // 64 MB  tiled [E][F/64][H/64][64][64]
  u16* w2t   = (u16*)(ws + 75497472ull);            // 64 MB  tiled [E][H/64][F/64][64][64]
  u16* hbuf  = (u16*)(ws + 142606336ull);           // 64 MB  [8192][F] bf16
  // ybuf reuses w1t's 64MB region: w1t is dead after gemm1, ybuf written by gemm2.
  float* ybuf = (float*)(ws + 8388608ull);          // 64 MB  2 slabs of [8192][H] f32
  int*   tki    = (int*)(ws + 209715200ull);
  float* tkw    = (float*)(ws + 209747968ull);
  int*   perm   = (int*)(ws + 209780736ull);
  float* pw     = (float*)(ws + 209813504ull);
  int*   counts = (int*)(ws + 209846272ull);        // counts[8], cursor[8], zsum
  int*   cursor = counts + 8;
  float* zsum   = (float*)(counts + 16);
  int*   islot  = (int*)(ws + 209846400ull);        // 32 KB  [T][2] slot map

  hipMemsetAsync(counts, 0, 128, stream);

  // W1 [E][H][F]: R=H(K), C=F(N) -> tiles [E][F/64][H/64]
  transpose_cvt_tiled<<<dim3(F_DIM / 64, H_DIM / 64, E_EXP), 256, 0, stream>>>(W1, w1t, H_DIM, F_DIM);
  // W2 [E][F][H]: R=F(K), C=H(N) -> tiles [E][H/64][F/64]
  transpose_cvt_tiled<<<dim3(H_DIM / 64, F_DIM / 64, E_EXP), 256, 0, stream>>>(W2, w2t, F_DIM, H_DIM);
  router_kernel<<<T_TOK / 16, 256, 0, stream>>>(x, Wr, br, xb, tki, tkw, counts, zsum);
  scatter_kernel<<<T_TOK / 256, 256, 0, stream>>>(tki, tkw, counts, cursor, perm, pw,
                                                  islot, zsum, out + OUT_ELEMS);
  gemm1_kernel<<<8192, 256, 0, stream>>>(xb, w1t, b1, perm, counts, hbuf);
  // 8 experts x 8 n-blocks x 2 K-splits x up to 32 m-blocks
  gemm2_kernel<<<4096, 256, 0, stream>>>(hbuf, w2t, b2, pw, counts, ybuf);
  combine_kernel<<<T_TOK, 256, 0, stream>>>(ybuf, islot, out);
}